// Round 9
// baseline (16604.352 us; speedup 1.0000x reference)
//
#include <hip/hip_runtime.h>
#include <stdint.h>
#include <math.h>

#define HD 1024
#define BB 8
#define LL 2048
#define NBLK 256
#define NTHR 512

typedef unsigned short u16;
typedef unsigned int u32;
typedef unsigned long long u64;

using bf16x8 = __attribute__((ext_vector_type(8))) short;
using f32x4  = __attribute__((ext_vector_type(4))) float;

__device__ __forceinline__ u16 f2bf(float f) {
  u32 x = __float_as_uint(f);
  x += 0x7fffu + ((x >> 16) & 1u);
  return (u16)(x >> 16);
}
__device__ __forceinline__ float bf2f(u16 u) {
  return __uint_as_float(((u32)u) << 16);
}
__device__ __forceinline__ float dot4(float4 a, float4 b) {
  return fmaf(a.x, b.x, fmaf(a.y, b.y, fmaf(a.z, b.z, a.w * b.w)));
}
__device__ __forceinline__ float sigmoidf(float x) { return 1.f / (1.f + expf(-x)); }
__device__ __forceinline__ float4 unpk4(u64 v) {
  float4 f;
  f.x = bf2f((u16)v);
  f.y = bf2f((u16)(v >> 16));
  f.z = bf2f((u16)(v >> 32));
  f.w = bf2f((u16)(v >> 48));
  return f;
}

// ---- self-tagged exchange lines: u64 = {2x bf16 data}<<32 | step tag ----
// One atomic load IS the barrier+data: no fences, no counters.
__device__ __forceinline__ float2 poll_line(const u64* p, u32 tag) {
  u64 v = __hip_atomic_load(p, __ATOMIC_RELAXED, __HIP_MEMORY_SCOPE_AGENT);
  while ((u32)v != tag) {
    __builtin_amdgcn_s_sleep(1);
    v = __hip_atomic_load(p, __ATOMIC_RELAXED, __HIP_MEMORY_SCOPE_AGENT);
  }
  u32 d = (u32)(v >> 32);
  float2 r;
  r.x = __uint_as_float((d & 0xffffu) << 16);
  r.y = __uint_as_float(d & 0xffff0000u);
  return r;
}
__device__ __forceinline__ void pub_line(u64* p, u32 tag, float a, float b) {
  u32 d = (u32)f2bf(a) | ((u32)f2bf(b) << 16);
  __hip_atomic_store(p, ((u64)d << 32) | (u64)tag,
                     __ATOMIC_RELAXED, __HIP_MEMORY_SCOPE_AGENT);
}

// ---------------- input LN: x [16384,1024] f32 -> xn bf16 ----------------
__global__ __launch_bounds__(256) void k_ln_x(const float* __restrict__ x,
    const float* __restrict__ g, const float* __restrict__ b,
    u16* __restrict__ xn) {
  int row = blockIdx.x;
  int t = threadIdx.x;
  const float4* xr = (const float4*)(x + (size_t)row * HD);
  float4 v = xr[t];
  float s = v.x + v.y + v.z + v.w;
  float ss = v.x * v.x + v.y * v.y + v.z * v.z + v.w * v.w;
#pragma unroll
  for (int off = 32; off; off >>= 1) { s += __shfl_down(s, off); ss += __shfl_down(ss, off); }
  __shared__ float red[8];
  if ((t & 63) == 0) { red[t >> 6] = s; red[4 + (t >> 6)] = ss; }
  __syncthreads();
  s = red[0] + red[1] + red[2] + red[3];
  ss = red[4] + red[5] + red[6] + red[7];
  float m = s * (1.0f / HD);
  float rstd = rsqrtf(ss * (1.0f / HD) - m * m + 1e-5f);
  float4 gv = ((const float4*)g)[t];
  float4 bv = ((const float4*)b)[t];
  ushort4 o;
  o.x = f2bf((v.x - m) * rstd * gv.x + bv.x);
  o.y = f2bf((v.y - m) * rstd * gv.y + bv.y);
  o.z = f2bf((v.z - m) * rstd * gv.z + bv.z);
  o.w = f2bf((v.w - m) * rstd * gv.w + bv.w);
  *(ushort4*)(xn + (size_t)row * HD + t * 4) = o;
}

// ---------------- output LN, in place on f32 rows ----------------
__global__ __launch_bounds__(256) void k_out_ln(float* __restrict__ y,
    const float* __restrict__ g, const float* __restrict__ b) {
  int row = blockIdx.x;
  int t = threadIdx.x;
  float4* yr = (float4*)(y + (size_t)row * HD);
  float4 v = yr[t];
  float s = v.x + v.y + v.z + v.w;
  float ss = v.x * v.x + v.y * v.y + v.z * v.z + v.w * v.w;
#pragma unroll
  for (int off = 32; off; off >>= 1) { s += __shfl_down(s, off); ss += __shfl_down(ss, off); }
  __shared__ float red[8];
  if ((t & 63) == 0) { red[t >> 6] = s; red[4 + (t >> 6)] = ss; }
  __syncthreads();
  s = red[0] + red[1] + red[2] + red[3];
  ss = red[4] + red[5] + red[6] + red[7];
  float m = s * (1.0f / HD);
  float rstd = rsqrtf(ss * (1.0f / HD) - m * m + 1e-5f);
  float4 gv = ((const float4*)g)[t];
  float4 bv = ((const float4*)b)[t];
  float4 o;
  o.x = (v.x - m) * rstd * gv.x + bv.x;
  o.y = (v.y - m) * rstd * gv.y + bv.y;
  o.z = (v.z - m) * rstd * gv.z + bv.z;
  o.w = (v.w - m) * rstd * gv.w + bv.w;
  yr[t] = o;
}

// ---------------- pack input-side weights to bf16: win=[3][1024][1024] ----
__global__ __launch_bounds__(256) void k_pack_win(const float* __restrict__ wz,
    const float* __restrict__ wr, const float* __restrict__ wh,
    u16* __restrict__ win) {
  int gid = blockIdx.x;           // 0..3071
  int gate = gid >> 10, o = gid & 1023;
  const float* w = (gate == 0) ? wz : ((gate == 1) ? wr : wh);
  const float* row = w + (size_t)o * (2 * HD);
  int t = threadIdx.x;
  float4 a = ((const float4*)row)[t];
  ushort4 ua;
  ua.x = f2bf(a.x); ua.y = f2bf(a.y); ua.z = f2bf(a.z); ua.w = f2bf(a.w);
  *(ushort4*)(win + (size_t)gid * HD + t * 4) = ua;
}

// ---------------- slice recurrent weights: Wrec[g][o][k] = w_g[o, H+k] ----
__global__ __launch_bounds__(256) void k_slice_w(const float* __restrict__ wz,
    const float* __restrict__ wr, const float* __restrict__ wh,
    float* __restrict__ Wrec) {
  int gid = blockIdx.x;
  int gate = gid >> 10, o = gid & 1023;
  const float* w = (gate == 0) ? wz : ((gate == 1) ? wr : wh);
  int t = threadIdx.x;
  float4 v = ((const float4*)(w + (size_t)o * (2 * HD) + HD))[t];
  ((float4*)(Wrec + ((size_t)gate << 20) + ((size_t)o << 10)))[t] = v;
}

// ---------------- bf16 MFMA GEMM: C[16384,3072] = A[16384,1024] * B[3072,1024]^T
__global__ __launch_bounds__(256) void k_gemm(const u16* __restrict__ A,
    const u16* __restrict__ Bw, u16* __restrict__ C) {
  __shared__ u16 As[128 * 32];
  __shared__ u16 Bs[128 * 32];
  int tid = threadIdx.x;
  int bx = blockIdx.x % 24;       // N tile
  int by = blockIdx.x / 24;       // M tile
  int m0 = by * 128, n0 = bx * 128;
  int lane = tid & 63, wave = tid >> 6;
  int wr = wave >> 1, wc = wave & 1;
  int rl = lane & 15, kq = (lane >> 4) * 8;
  f32x4 acc[4][4] = {};
  int srow = tid >> 2, skb = (tid & 3) * 8;
  for (int k0 = 0; k0 < 1024; k0 += 32) {
    __syncthreads();
#pragma unroll
    for (int i = 0; i < 2; i++) {
      int row = srow + i * 64;
      uint4 av = *(const uint4*)(A + (size_t)(m0 + row) * 1024 + k0 + skb);
      *(uint4*)(As + row * 32 + skb) = av;
      uint4 bv = *(const uint4*)(Bw + (size_t)(n0 + row) * 1024 + k0 + skb);
      *(uint4*)(Bs + row * 32 + skb) = bv;
    }
    __syncthreads();
    bf16x8 af[4], bg[4];
#pragma unroll
    for (int mi = 0; mi < 4; mi++)
      af[mi] = *(const bf16x8*)(As + (wr * 64 + mi * 16 + rl) * 32 + kq);
#pragma unroll
    for (int ni = 0; ni < 4; ni++)
      bg[ni] = *(const bf16x8*)(Bs + (wc * 64 + ni * 16 + rl) * 32 + kq);
#pragma unroll
    for (int mi = 0; mi < 4; mi++)
#pragma unroll
      for (int ni = 0; ni < 4; ni++)
        acc[mi][ni] = __builtin_amdgcn_mfma_f32_16x16x32_bf16(af[mi], bg[ni], acc[mi][ni], 0, 0, 0);
  }
  int rowq = (lane >> 4) * 4;
#pragma unroll
  for (int mi = 0; mi < 4; mi++)
#pragma unroll
    for (int ni = 0; ni < 4; ni++)
#pragma unroll
      for (int r = 0; r < 4; r++) {
        int row = m0 + wr * 64 + mi * 16 + rowq + r;
        int col = n0 + wc * 64 + ni * 16 + rl;
        C[(size_t)row * 3072 + col] = f2bf(acc[mi][ni][r]);
      }
}

// ---------------- init tagged h lines (tag 0, slot 0) ----------------
__global__ __launch_bounds__(256) void k_init_hx(const float* __restrict__ h0,
    u64* __restrict__ hx) {
  int i = blockIdx.x * 256 + threadIdx.x;   // 0..4095
  int b = i >> 9, line = i & 511;
  float2 v = ((const float2*)h0)[i];        // elems (2i, 2i+1) = batch b, 2*line
  u32 d = (u32)f2bf(v.x) | ((u32)f2bf(v.y) << 16);
  hx[(size_t)b * 1024 + line] = ((u64)d << 32);   // slot 0, tag 0
}

// ---------------- persistent recurrence kernel, dataflow-sync --------------
// 256 blocks = 8 batches x 32 output-blocks (bid = b*32+ob). Wave w8 owns
// outputs o0..o0+3 (all lanes carry all 4). Exchange via self-tagged u64
// lines (2x bf16 + step tag), double-buffered by parity; no barriers.
__global__ __launch_bounds__(NTHR, 1) void k_rec(
    u64* __restrict__ hx, u64* __restrict__ rx,
    const float* __restrict__ Wrec, const u16* __restrict__ gx,
    const float* __restrict__ bz, const float* __restrict__ br,
    const float* __restrict__ bh, const float* __restrict__ g_st,
    const float* __restrict__ b_st, const float* __restrict__ h0,
    float* __restrict__ out, float* __restrict__ hfin) {
  __shared__ float hn_s[HD];
  __shared__ float u_s[HD];
  __shared__ float2 red2[8];
  const int t = threadIdx.x;
  const int bid = blockIdx.x;
  const int b = bid >> 5, ob = bid & 31;
  const int w8 = t >> 6, ln = t & 63;
  const int o0 = ob * 32 + w8 * 4;

  const float4* wrow = (const float4*)(Wrec + (size_t)o0 * HD);
  const float4 bz4 = *(const float4*)(bz + o0);
  const float4 br4 = *(const float4*)(br + o0);
  const float4 bh4 = *(const float4*)(bh + o0);
  const float2 gm2 = ((const float2*)g_st)[t];
  const float2 bt2 = ((const float2*)b_st)[t];
  const u16* gbase = gx + ((size_t)b * LL) * 3072 + o0;
  float* outp = out + ((size_t)b * LL) * HD + o0;
  u64* hx_b = hx + (size_t)b * 1024;       // 2 parity slots x 512 lines
  u64* rx_b = rx + (size_t)b * 1024;
  const int publine = ob * 16 + w8 * 2 + (ln & 1);   // used by lanes 0,1

  float4 hom = *(const float4*)(h0 + b * HD + o0);   // fp32 master state
  u64 gz8 = *(const u64*)(gbase);
  u64 gr8 = *(const u64*)(gbase + 1024);
  u64 gh8 = *(const u64*)(gbase + 2048);

  for (int step = 0; step < LL; step++) {
    const int par = step & 1;
    // ---- poll h (tag==step), LN stats ----
    float2 h2 = poll_line(hx_b + par * 512 + t, (u32)step);
    float s = h2.x + h2.y;
    float ss = fmaf(h2.x, h2.x, h2.y * h2.y);
#pragma unroll
    for (int mk = 1; mk < 64; mk <<= 1) { s += __shfl_xor(s, mk); ss += __shfl_xor(ss, mk); }
    if (ln == 0) { float2 rv; rv.x = s; rv.y = ss; red2[w8] = rv; }
    __syncthreads();
    s = 0.f; ss = 0.f;
#pragma unroll
    for (int i = 0; i < 8; i++) { float2 rv = red2[i]; s += rv.x; ss += rv.y; }
    float m = s * (1.0f / HD);
    float rstd = rsqrtf(ss * (1.0f / HD) - m * m + 1e-5f);
    float2 hn;
    hn.x = fmaf((h2.x - m) * rstd, gm2.x, bt2.x);
    hn.y = fmaf((h2.y - m) * rstd, gm2.y, bt2.y);
    ((float2*)hn_s)[t] = hn;
    __syncthreads();
    // ---- hn slice, conflict-free: lane stride 16B ----
    float4 hsl[4];
#pragma unroll
    for (int jj = 0; jj < 4; jj++) hsl[jj] = ((const float4*)hn_s)[jj * 64 + ln];
    // ---- r gate first: compute + publish tagged ----
    float a0 = 0.f, a1 = 0.f, a2 = 0.f, a3 = 0.f;
#pragma unroll
    for (int jj = 0; jj < 4; jj++) {
      int idx = (1 << 18) + jj * 64 + ln;
      a0 += dot4(wrow[idx], hsl[jj]);
      a1 += dot4(wrow[idx + 256], hsl[jj]);
      a2 += dot4(wrow[idx + 512], hsl[jj]);
      a3 += dot4(wrow[idx + 768], hsl[jj]);
    }
#pragma unroll
    for (int mk = 1; mk < 64; mk <<= 1) {
      a0 += __shfl_xor(a0, mk); a1 += __shfl_xor(a1, mk);
      a2 += __shfl_xor(a2, mk); a3 += __shfl_xor(a3, mk);
    }
    float4 gr4 = unpk4(gr8);
    float r0 = sigmoidf(a0 + gr4.x + br4.x);
    float r1 = sigmoidf(a1 + gr4.y + br4.y);
    float r2v = sigmoidf(a2 + gr4.z + br4.z);
    float r3v = sigmoidf(a3 + gr4.w + br4.w);
    if (ln < 2) {
      float pa = ln ? r2v : r0;
      float pb = ln ? r3v : r1;
      pub_line(rx_b + par * 512 + publine, (u32)step, pa, pb);
    }
    // ---- z gate (overlaps other blocks' r publishes) ----
    a0 = 0.f; a1 = 0.f; a2 = 0.f; a3 = 0.f;
#pragma unroll
    for (int jj = 0; jj < 4; jj++) {
      int idx = jj * 64 + ln;
      a0 += dot4(wrow[idx], hsl[jj]);
      a1 += dot4(wrow[idx + 256], hsl[jj]);
      a2 += dot4(wrow[idx + 512], hsl[jj]);
      a3 += dot4(wrow[idx + 768], hsl[jj]);
    }
#pragma unroll
    for (int mk = 1; mk < 64; mk <<= 1) {
      a0 += __shfl_xor(a0, mk); a1 += __shfl_xor(a1, mk);
      a2 += __shfl_xor(a2, mk); a3 += __shfl_xor(a3, mk);
    }
    float4 gz4 = unpk4(gz8);
    float4 zv;
    zv.x = sigmoidf(a0 + gz4.x + bz4.x);
    zv.y = sigmoidf(a1 + gz4.y + bz4.y);
    zv.z = sigmoidf(a2 + gz4.z + bz4.z);
    zv.w = sigmoidf(a3 + gz4.w + bz4.w);
    // ---- poll r (tag==step), u = r*hn -> LDS ----
    float2 r2 = poll_line(rx_b + par * 512 + t, (u32)step);
    float2 u2;
    u2.x = r2.x * hn.x;
    u2.y = r2.y * hn.y;
    ((float2*)u_s)[t] = u2;
    __syncthreads();
    // ---- h_cand dot + state update ----
    a0 = 0.f; a1 = 0.f; a2 = 0.f; a3 = 0.f;
#pragma unroll
    for (int jj = 0; jj < 4; jj++) {
      float4 u4 = ((const float4*)u_s)[jj * 64 + ln];
      int idx = (2 << 18) + jj * 64 + ln;
      a0 += dot4(wrow[idx], u4);
      a1 += dot4(wrow[idx + 256], u4);
      a2 += dot4(wrow[idx + 512], u4);
      a3 += dot4(wrow[idx + 768], u4);
    }
#pragma unroll
    for (int mk = 1; mk < 64; mk <<= 1) {
      a0 += __shfl_xor(a0, mk); a1 += __shfl_xor(a1, mk);
      a2 += __shfl_xor(a2, mk); a3 += __shfl_xor(a3, mk);
    }
    float4 gh4 = unpk4(gh8);
    float4 hnew;
    hnew.x = fmaf(zv.x, tanhf(a0 + gh4.x + bh4.x) - hom.x, hom.x);
    hnew.y = fmaf(zv.y, tanhf(a1 + gh4.y + bh4.y) - hom.y, hom.y);
    hnew.z = fmaf(zv.z, tanhf(a2 + gh4.z + bh4.z) - hom.z, hom.z);
    hnew.w = fmaf(zv.w, tanhf(a3 + gh4.w + bh4.w) - hom.w, hom.w);
    hom = hnew;
    if (ln < 2) {
      float pa = ln ? hnew.z : hnew.x;
      float pb = ln ? hnew.w : hnew.y;
      pub_line(hx_b + (par ^ 1) * 512 + publine, (u32)(step + 1), pa, pb);
    }
    // ---- out store (fp32 from master) + next gx prefetch ----
    float hsel = (ln == 0) ? hnew.x : ((ln == 1) ? hnew.y : ((ln == 2) ? hnew.z : hnew.w));
    if (ln < 4) outp[ln] = hsel;
    outp += HD;
    if (step == LL - 1 && ln < 4) hfin[b * HD + o0 + ln] = hsel;
    int ns = (step + 1 < LL) ? (step + 1) : step;
    const u16* gn = gbase + (size_t)ns * 3072;
    gz8 = *(const u64*)(gn);
    gr8 = *(const u64*)(gn + 1024);
    gh8 = *(const u64*)(gn + 2048);
  }
}

__global__ __launch_bounds__(256) void k_copy(const float* __restrict__ src,
    float* __restrict__ dst, int n4) {
  int i = blockIdx.x * blockDim.x + threadIdx.x;
  if (i < n4) ((float4*)dst)[i] = ((const float4*)src)[i];
}

extern "C" void kernel_launch(void* const* d_in, const int* in_sizes, int n_in,
                              void* d_out, int out_size, void* d_ws, size_t ws_size,
                              hipStream_t stream) {
  (void)in_sizes; (void)n_in; (void)out_size; (void)ws_size;
  const float* x    = (const float*)d_in[0];
  const float* h0   = (const float*)d_in[1];
  const float* wz   = (const float*)d_in[2];
  const float* bz   = (const float*)d_in[3];
  const float* wr   = (const float*)d_in[4];
  const float* br   = (const float*)d_in[5];
  const float* wh   = (const float*)d_in[6];
  const float* bh   = (const float*)d_in[7];
  const float* g_in = (const float*)d_in[8];
  const float* b_in = (const float*)d_in[9];
  const float* g_st = (const float*)d_in[10];
  const float* b_st = (const float*)d_in[11];
  const float* g_out= (const float*)d_in[12];
  const float* b_out= (const float*)d_in[13];
  float* out = (float*)d_out;

  char* ws = (char*)d_ws;
  // region A [0,32MB): xn during frontend; raw recurrent fp32 weights after
  u16*   xn   = (u16*)(ws);
  float* Wrec = (float*)(ws);                       // 12 MB (after gemm)
  // region B: input-side bf16 weights
  u16*   win  = (u16*)(ws + 33554432ull);           //  6 MB
  // region C: gx
  u16*   gx   = (u16*)(ws + 39845888ull);           // 96 MB -> ends 140509184
  // region D: tagged exchange buffers + final state
  u64*   hx   = (u64*)(ws + 140509184ull);          // 64 KB (8 x 2par x 512)
  u64*   rx   = (u64*)(ws + 140574720ull);          // 64 KB
  float* hfin = (float*)(ws + 140640256ull);        // 32 KB

  k_pack_win<<<dim3(3072), dim3(256), 0, stream>>>(wz, wr, wh, win);
  k_ln_x<<<dim3(16384), dim3(256), 0, stream>>>(x, g_in, b_in, xn);
  k_gemm<<<dim3(3072), dim3(256), 0, stream>>>(xn, win, gx);
  // after gemm: xn region is dead -> write raw recurrent weights there
  k_slice_w<<<dim3(3072), dim3(256), 0, stream>>>(wz, wr, wh, Wrec);
  // invalidate all tags (0xFF != any step), then write tag-0 h lines
  hipMemsetAsync(hx, 0xFF, 131072, stream);
  k_init_hx<<<dim3(16), dim3(256), 0, stream>>>(h0, hx);
  k_rec<<<dim3(NBLK), dim3(NTHR), 0, stream>>>(hx, rx, Wrec, gx, bz, br, bh,
                                               g_st, b_st, h0, out, hfin);
  k_out_ln<<<dim3(16384), dim3(256), 0, stream>>>(out, g_out, b_out);
  k_copy<<<dim3(8), dim3(256), 0, stream>>>(hfin, out + (size_t)16384 * 1024, 2048);
}